// Round 8
// baseline (317.591 us; speedup 1.0000x reference)
//
#include <hip/hip_runtime.h>
#include <stdint.h>
#include <math.h>

#define T_DIM 8192
#define D_DIM 4096
#define E_DIM 64
#define TE (T_DIM * E_DIM)  // 524288
#define GAP_MARGIN 2e-3     // > 2x provable worst-case bf16-split logit error (9.4e-4)
#define ROWS 32             // rows per block (mfma kernel)
#define BK 256              // k per chunk
#define NCHUNK (D_DIM / BK) // 16

typedef __attribute__((ext_vector_type(8))) short short8_t;  // 8 bf16 (4 VGPRs)
typedef __attribute__((ext_vector_type(4))) float f32x4;

// Raw barrier: LDS-drain only. Does NOT drain vmcnt -> global loads (A
// prefetch regs, B fragment regs) stay in flight across chunk barriers.
// __syncthreads() would emit s_waitcnt vmcnt(0) and kill the pipeline.
#define BAR() do {                                            \
    asm volatile("s_waitcnt lgkmcnt(0)" ::: "memory");        \
    __builtin_amdgcn_s_barrier();                             \
    asm volatile("" ::: "memory");                            \
  } while (0)

// ============================================================================
// W bf16 hi/lo planes, fragment-linear: idx = ks*2048 + subE*512 + q*128 +
// ee*8 + j  (e = subE*16+ee, k = ks*32 + q*8 + j). Wave B-read = coalesced
// 1KB global_load_dwordx4. B never touches LDS.
// ============================================================================
__device__ __align__(16) short Whi_g[E_DIM * D_DIM];  // 512 KB
__device__ __align__(16) short Wlo_g[E_DIM * D_DIM];  // 512 KB

// ============================================================================
// Threefry-2x32, key = (0, 42), 20 rounds — VALIDATED (prior session r3/4/5)
// ============================================================================
__device__ __forceinline__ void threefry2x32_k42(uint32_t x0, uint32_t x1,
                                                 uint32_t& o0, uint32_t& o1) {
  const uint32_t ks0 = 0u, ks1 = 42u;
  const uint32_t ks2 = 0x1BD11BDAu ^ ks0 ^ ks1;
  x0 += ks0; x1 += ks1;
#define TF_RND(r) { x0 += x1; x1 = (x1 << (r)) | (x1 >> (32 - (r))); x1 ^= x0; }
  TF_RND(13) TF_RND(15) TF_RND(26) TF_RND(6)   x0 += ks1; x1 += ks2 + 1u;
  TF_RND(17) TF_RND(29) TF_RND(16) TF_RND(24)  x0 += ks2; x1 += ks0 + 2u;
  TF_RND(13) TF_RND(15) TF_RND(26) TF_RND(6)   x0 += ks0; x1 += ks1 + 3u;
  TF_RND(17) TF_RND(29) TF_RND(16) TF_RND(24)  x0 += ks1; x1 += ks2 + 4u;
  TF_RND(13) TF_RND(15) TF_RND(26) TF_RND(6)   x0 += ks2; x1 += ks0 + 5u;
#undef TF_RND
  o0 = x0; o1 = x1;
}

__device__ __forceinline__ uint32_t jax_random_bits32(uint32_t j) {
  uint32_t o0, o1;
  threefry2x32_k42(0u, j, o0, o1);
  return o0 ^ o1;
}

// f64 finalize per row (lane = expert) — VALIDATED, unchanged
__device__ __forceinline__ void finalize_row_f64(double logit, int e, int t,
                                                 float& mask_out, float& weight_out,
                                                 double& gap_out) {
  double m = logit;
#pragma unroll
  for (int off = 1; off < 64; off <<= 1) {
    const double om = __shfl_xor(m, off, 64);
    m = (om > m) ? om : m;
  }
  const double pe = exp(logit - m);
  double s = pe;
#pragma unroll
  for (int off = 1; off < 64; off <<= 1) s += __shfl_xor(s, off, 64);
  weight_out = (float)(pe / s);

  const int idx = t * 64 + e;
  const uint32_t bits = jax_random_bits32((uint32_t)idx);
  const float f01 = __uint_as_float((bits >> 9) | 0x3f800000u) - 1.0f;
  const float minv = 1e-6f;
  const float maxv = 0.999999f;
  float u = __fadd_rn(__fmul_rn(f01, maxv - minv), minv);
  u = fmaxf(minv, u);
  const double g = -log(-log((double)u));
  const double sel = logit + g;

  float mask = 0.0f;
  double cur = sel;
  double v8 = 0.0, v9 = 0.0;
  for (int it = 0; it < 9; ++it) {
    double v = cur;
    int vi = e;
#pragma unroll
    for (int off = 1; off < 64; off <<= 1) {
      const double ov = __shfl_xor(v, off, 64);
      const int    oi = __shfl_xor(vi, off, 64);
      if (ov > v || (ov == v && oi < vi)) { v = ov; vi = oi; }
    }
    if (it < 8) {
      if (vi == e) { mask = 1.0f; cur = -__builtin_inf(); }
      if (it == 7) v8 = v;
    } else {
      v9 = v;
    }
  }
  mask_out = mask;
  gap_out = v8 - v9;
}

// fp32 -> bf16 (RNE, finite inputs only)
__device__ __forceinline__ uint16_t f2bf(float f) {
  const uint32_t x = __float_as_uint(f);
  return (uint16_t)((x + 0x7FFFu + ((x >> 16) & 1u)) >> 16);
}

// split 4 floats into bf16 hi/lo ushort4 (same element-wise math as split8)
__device__ __forceinline__ void split4(const float4 v, ushort4& hi, ushort4& lo) {
  float fh;
  hi.x = f2bf(v.x); fh = __uint_as_float((uint32_t)hi.x << 16); lo.x = f2bf(v.x - fh);
  hi.y = f2bf(v.y); fh = __uint_as_float((uint32_t)hi.y << 16); lo.y = f2bf(v.y - fh);
  hi.z = f2bf(v.z); fh = __uint_as_float((uint32_t)hi.z << 16); lo.z = f2bf(v.z - fh);
  hi.w = f2bf(v.w); fh = __uint_as_float((uint32_t)hi.w << 16); lo.w = f2bf(v.w - fh);
}

// split 8 consecutive floats (w_split_kernel only)
__device__ __forceinline__ void split8(const float4 a, const float4 b,
                                       short8_t& hi, short8_t& lo) {
  const float f[8] = {a.x, a.y, a.z, a.w, b.x, b.y, b.z, b.w};
#pragma unroll
  for (int j = 0; j < 8; ++j) {
    const uint16_t hb = f2bf(f[j]);
    const float fh = __uint_as_float((uint32_t)hb << 16);
    const uint16_t lb = f2bf(f[j] - fh);
    hi[j] = (short)hb;
    lo[j] = (short)lb;
  }
}

// ============================================================================
// Pre-kernel: split W (fp32, 1 MB) into bf16 hi/lo planes, fragment-linear.
// ============================================================================
__global__ __launch_bounds__(256)
void w_split_kernel(const float* __restrict__ W) {
  const int g = blockIdx.x * 256 + threadIdx.x;  // 0..16383
#pragma unroll
  for (int r = 0; r < 2; ++r) {
    const int u = g * 2 + r;        // unit id 0..32767 (one unit = 8 k of one e)
    const int e = u >> 9;           // 512 k-octets per expert
    const int k0 = (u & 511) * 8;
    const float* wp = W + (size_t)e * D_DIM + k0;
    const float4 a = *reinterpret_cast<const float4*>(wp);
    const float4 b = *reinterpret_cast<const float4*>(wp + 4);
    short8_t hi, lo;
    split8(a, b, hi, lo);
    const int ks = k0 >> 5, q = (k0 >> 3) & 3;
    const int subE = e >> 4, ee = e & 15;
    const int idx = ks * 2048 + subE * 512 + q * 128 + ee * 8;
    *reinterpret_cast<short8_t*>(Whi_g + idx) = hi;
    *reinterpret_cast<short8_t*>(Wlo_g + idx) = lo;
  }
}

// ============================================================================
// MFMA router kernel. 256 blocks x 256 threads (4 waves). Block: 32 rows x
// 64 e. Wave n (=wave id) owns ALL 32 rows x experts n*16..+15 as TWO
// m-subtiles sharing the same B fragments (register blocking): B L2 traffic
// halves to 256 MB total, zero duplication. 1 block/CU.
//
// A global loads: thread (r = tid>>3, j = tid&7) reads col s*32 + j*4 for
// every kstep s -> each load instr covers 8 FULL 128B lines (coalesced; the
// old mapping fetched 64 lines using 16B each = 8x overfetch).
// A LDS: unit u = s*128 + q*32 + row (16B units); thread writes 2x ds_write_b64
// per kstep at u*16 + half*8 (4-way balanced = b64 HW minimum). Read:
// ds_read_b128 at u = s*128 + (lane>>4)*32 + mm*16 + (lane&15) (8-way
// balanced = b128 HW minimum). No swizzle needed — both patterns are
// naturally bank-balanced (round-6/7's pseudo-swizzle CREATED 1.06M conflicts).
// Pipeline: full-chunk B preload (16 regs) issued before the split phase
// (~800cy VALU covers L2 latency); depth-2 A prefetch across BAR (no vmcnt
// drain). __launch_bounds__(256,1): 1 wave/SIMD — ILP is the only latency
// hider, give the allocator the whole register file (round-5/7 lesson).
// Validated 3-product split order per acc (Alo*Bhi + Ahi*Blo + Ahi*Bhi).
// ============================================================================
__global__ __launch_bounds__(256, 1)
void router_mfma_kernel(const float* __restrict__ h,
                        const float* __restrict__ bias,
                        float* __restrict__ out,
                        unsigned char* __restrict__ flags) {
  __shared__ __align__(16) short Ahi[2][ROWS * BK];  // 2 x 16 KB
  __shared__ __align__(16) short Alo[2][ROWS * BK];  // 2 x 16 KB
  __shared__ float logits_lds[ROWS * 65];            // 8.3 KB, +1 pad

  const int tid  = threadIdx.x;
  const int wave = tid >> 6;   // n: experts wave*16..+15
  const int lane = tid & 63;
  const int row0 = blockIdx.x * ROWS;

  // ---- A staging: thread (row r, q-half j); per kstep s: col = s*32 + j*4
  const int r = tid >> 3;              // 0..31
  const int j = tid & 7;               // 0..7
  const int qW = j >> 1, halfW = j & 1;
  const float* hst = h + (size_t)(row0 + r) * D_DIM + j * 4;
  // short offset for kstep s: (s*128 + qW*32 + r)*8 + halfW*4
  const int wbase = (qW * 32 + r) * 8 + halfW * 4;

  // ---- A fragment read base: u = s*128 + (lane>>4)*32 + mm*16 + (lane&15)
  const int arbase = (lane >> 4) * 32 + (lane & 15);

  // ---- B fragment base: ee = lane&15, q = lane>>4, expert block = wave
  const int b_off = wave * 512 + (lane >> 4) * 128 + (lane & 15) * 8;

  f32x4 accA = {0.0f, 0.0f, 0.0f, 0.0f};
  f32x4 accB = {0.0f, 0.0f, 0.0f, 0.0f};

  // depth-2 A prefetch: 8 float4 per set (one per kstep), named regs
  float4 Ra0, Ra1, Ra2, Ra3, Ra4, Ra5, Ra6, Ra7;
  float4 Rb0, Rb1, Rb2, Rb3, Rb4, Rb5, Rb6, Rb7;
#define LOADSET(P0,P1,P2,P3,P4,P5,P6,P7, CC)                                   \
  { const float* p_ = hst + (CC) * BK;                                         \
    P0 = *reinterpret_cast<const float4*>(p_ + 0 * 32);                        \
    P1 = *reinterpret_cast<const float4*>(p_ + 1 * 32);                        \
    P2 = *reinterpret_cast<const float4*>(p_ + 2 * 32);                        \
    P3 = *reinterpret_cast<const float4*>(p_ + 3 * 32);                        \
    P4 = *reinterpret_cast<const float4*>(p_ + 4 * 32);                        \
    P5 = *reinterpret_cast<const float4*>(p_ + 5 * 32);                        \
    P6 = *reinterpret_cast<const float4*>(p_ + 6 * 32);                        \
    P7 = *reinterpret_cast<const float4*>(p_ + 7 * 32); }

  LOADSET(Ra0,Ra1,Ra2,Ra3,Ra4,Ra5,Ra6,Ra7, 0)
  LOADSET(Rb0,Rb1,Rb2,Rb3,Rb4,Rb5,Rb6,Rb7, 1)

#define SPLITW(S, RV)                                                          \
  { ushort4 hi_, lo_;                                                          \
    split4(RV, hi_, lo_);                                                      \
    *reinterpret_cast<ushort4*>(&Ahi[BUF_][(S) * 1024 + wbase]) = hi_;         \
    *reinterpret_cast<ushort4*>(&Alo[BUF_][(S) * 1024 + wbase]) = lo_; }

#define KSTEP(S, BH, BL)                                                       \
  { const int u0_ = (S) * 128 + arbase;                                        \
    const short8_t ah0 = *reinterpret_cast<const short8_t*>(&Ahi[BUF_][u0_ * 8]);        \
    const short8_t al0 = *reinterpret_cast<const short8_t*>(&Alo[BUF_][u0_ * 8]);        \
    const short8_t ah1 = *reinterpret_cast<const short8_t*>(&Ahi[BUF_][(u0_ + 16) * 8]); \
    const short8_t al1 = *reinterpret_cast<const short8_t*>(&Alo[BUF_][(u0_ + 16) * 8]); \
    accA = __builtin_amdgcn_mfma_f32_16x16x32_bf16(al0, BH, accA, 0, 0, 0);    \
    accA = __builtin_amdgcn_mfma_f32_16x16x32_bf16(ah0, BL, accA, 0, 0, 0);    \
    accA = __builtin_amdgcn_mfma_f32_16x16x32_bf16(ah0, BH, accA, 0, 0, 0);    \
    accB = __builtin_amdgcn_mfma_f32_16x16x32_bf16(al1, BH, accB, 0, 0, 0);    \
    accB = __builtin_amdgcn_mfma_f32_16x16x32_bf16(ah1, BL, accB, 0, 0, 0);    \
    accB = __builtin_amdgcn_mfma_f32_16x16x32_bf16(ah1, BH, accB, 0, 0, 0); }

#define CHUNK_STEP(P0,P1,P2,P3,P4,P5,P6,P7, BUF, CC)                           \
  { const int BUF_ = (BUF);                                                    \
    /* B preload: whole chunk, 16 independent coalesced loads */               \
    const size_t bb_ = (size_t)((CC) * 8) * 2048 + b_off;                      \
    const short8_t BH0 = *reinterpret_cast<const short8_t*>(Whi_g + bb_ + 0 * 2048); \
    const short8_t BH1 = *reinterpret_cast<const short8_t*>(Whi_g + bb_ + 1 * 2048); \
    const short8_t BH2 = *reinterpret_cast<const short8_t*>(Whi_g + bb_ + 2 * 2048); \
    const short8_t BH3 = *reinterpret_cast<const short8_t*>(Whi_g + bb_ + 3 * 2048); \
    const short8_t BH4 = *reinterpret_cast<const short8_t*>(Whi_g + bb_ + 4 * 2048); \
    const short8_t BH5 = *reinterpret_cast<const short8_t*>(Whi_g + bb_ + 5 * 2048); \
    const short8_t BH6 = *reinterpret_cast<const short8_t*>(Whi_g + bb_ + 6 * 2048); \
    const short8_t BH7 = *reinterpret_cast<const short8_t*>(Whi_g + bb_ + 7 * 2048); \
    const short8_t BL0 = *reinterpret_cast<const short8_t*>(Wlo_g + bb_ + 0 * 2048); \
    const short8_t BL1 = *reinterpret_cast<const short8_t*>(Wlo_g + bb_ + 1 * 2048); \
    const short8_t BL2 = *reinterpret_cast<const short8_t*>(Wlo_g + bb_ + 2 * 2048); \
    const short8_t BL3 = *reinterpret_cast<const short8_t*>(Wlo_g + bb_ + 3 * 2048); \
    const short8_t BL4 = *reinterpret_cast<const short8_t*>(Wlo_g + bb_ + 4 * 2048); \
    const short8_t BL5 = *reinterpret_cast<const short8_t*>(Wlo_g + bb_ + 5 * 2048); \
    const short8_t BL6 = *reinterpret_cast<const short8_t*>(Wlo_g + bb_ + 6 * 2048); \
    const short8_t BL7 = *reinterpret_cast<const short8_t*>(Wlo_g + bb_ + 7 * 2048); \
    /* split prefetched A -> LDS (VALU phase covers B L2 latency) */           \
    SPLITW(0, P0) SPLITW(1, P1) SPLITW(2, P2) SPLITW(3, P3)                    \
    SPLITW(4, P4) SPLITW(5, P5) SPLITW(6, P6) SPLITW(7, P7)                    \
    BAR();                                                                     \
    /* A prefetch for chunk CC+2 — survives BAR (no vmcnt drain) */            \
    if ((CC) + 2 < NCHUNK) {                                                   \
      LOADSET(P0,P1,P2,P3,P4,P5,P6,P7, (CC) + 2)                               \
    }                                                                          \
    KSTEP(0, BH0, BL0) KSTEP(1, BH1, BL1) KSTEP(2, BH2, BL2)                   \
    KSTEP(3, BH3, BL3) KSTEP(4, BH4, BL4) KSTEP(5, BH5, BL5)                   \
    KSTEP(6, BH6, BL6) KSTEP(7, BH7, BL7)                                      \
    BAR();  /* readers of buf done before it is overwritten at CC+2 */         \
  }

  for (int c = 0; c < NCHUNK; c += 2) {
    CHUNK_STEP(Ra0,Ra1,Ra2,Ra3,Ra4,Ra5,Ra6,Ra7, 0, c)
    CHUNK_STEP(Rb0,Rb1,Rb2,Rb3,Rb4,Rb5,Rb6,Rb7, 1, c + 1)
  }
#undef CHUNK_STEP
#undef KSTEP
#undef SPLITW
#undef LOADSET

  // epilogue: C/D layout col=lane&15, row=(lane>>4)*4+reg -> logits LDS
  {
    const int q   = lane >> 4;
    const int col = wave * 16 + (lane & 15);
#pragma unroll
    for (int reg = 0; reg < 4; ++reg) {
      logits_lds[(q * 4 + reg) * 65 + col]      = accA[reg];  // mm = 0
      logits_lds[(16 + q * 4 + reg) * 65 + col] = accB[reg];  // mm = 1
    }
  }
  __syncthreads();

  // finalize: wave handles rows 8*wave..+7, lane = expert — VALIDATED path
  const int e = lane;
  const double be = (double)bias[e];
  for (int rr = 0; rr < 8; ++rr) {
    const int rloc = wave * 8 + rr;
    const int t = row0 + rloc;
    const double logit = (double)logits_lds[rloc * 65 + e] + be;

    float mask, weight;
    double gap;
    finalize_row_f64(logit, e, t, mask, weight, gap);

    const int idx = t * 64 + e;
    out[idx]          = mask;
    out[TE + idx]     = weight;
    out[2 * TE + idx] = (float)logit;
    if (e == 0) flags[t] = (gap < GAP_MARGIN) ? 1 : 0;
  }
}

// ============================================================================
// Fixup kernel — COALESCED W reads (the old lane=expert scatter fetched 64
// 128B lines per instr using 16B each = 8 MB per flagged row; this reads
// exactly 1 MB). One block (512 thr, 8 waves) per row, early exit. Wave w
// owns experts w*8..+7 over full D: lanes read contiguous 1KB W per instr,
// h broadcast-free from LDS (b128, bank-balanced), 4 f64 chains, f64
// butterfly reduce. Same pure-f64 sums + VALIDATED finalize.
// ============================================================================
__global__ __launch_bounds__(512)
void router_fixup_kernel(const float* __restrict__ h,
                         const float* __restrict__ W,
                         const float* __restrict__ bias,
                         const unsigned char* __restrict__ flags,
                         float* __restrict__ out) {
  const int t = blockIdx.x;
  if (flags[t] == 0) return;

  __shared__ float  h_lds[D_DIM];  // 16 KB
  __shared__ double red[64];

  const int tid  = threadIdx.x;
  const int wv   = tid >> 6;
  const int lane = tid & 63;

  // stage h row, coalesced float4 (512 thr x 2 x 16B = 16 KB)
  {
    const float4* hrow4 = reinterpret_cast<const float4*>(h + (size_t)t * D_DIM);
    float4* hl4 = reinterpret_cast<float4*>(h_lds);
    hl4[tid]       = hrow4[tid];
    hl4[tid + 512] = hrow4[tid + 512];
  }
  __syncthreads();

  // wave wv handles experts wv*8 .. wv*8+7 over full D
  for (int ei = 0; ei < 8; ++ei) {
    const int e = wv * 8 + ei;
    const float4* wrow = reinterpret_cast<const float4*>(W + (size_t)e * D_DIM);
    const float4* hl4  = reinterpret_cast<const float4*>(h_lds);
    double a0 = 0.0, a1 = 0.0, a2 = 0.0, a3 = 0.0;
#pragma unroll
    for (int i = 0; i < 16; ++i) {
      const float4 w  = wrow[i * 64 + lane];
      const float4 hh = hl4[i * 64 + lane];
      a0 = fma((double)w.x, (double)hh.x, a0);
      a1 = fma((double)w.y, (double)hh.y, a1);
      a2 = fma((double)w.z, (double)hh.z, a2);
      a3 = fma((double)w.w, (double)hh.w, a3);
    }
    double s = (a0 + a1) + (a2 + a3);
#pragma unroll
    for (int off = 1; off < 64; off <<= 1) s += __shfl_xor(s, off, 64);
    if (lane == 0) red[e] = s;
  }
  __syncthreads();

  if (wv == 0) {
    const int e = lane;
    const double logit = red[e] + (double)bias[e];
    float mask, weight;
    double gap;
    finalize_row_f64(logit, e, t, mask, weight, gap);

    const int idx = t * 64 + e;
    out[idx]          = mask;
    out[TE + idx]     = weight;
    out[2 * TE + idx] = (float)logit;
  }
}

extern "C" void kernel_launch(void* const* d_in, const int* in_sizes, int n_in,
                              void* d_out, int out_size, void* d_ws, size_t ws_size,
                              hipStream_t stream) {
  const float* h    = (const float*)d_in[0];
  const float* W    = (const float*)d_in[1];
  const float* bias = (const float*)d_in[2];
  // d_in[3] = k (always 8) — hard-coded top-8
  float* out = (float*)d_out;
  unsigned char* flags = (unsigned char*)d_ws;  // 8192 B, fully rewritten per call

  w_split_kernel<<<64, 256, 0, stream>>>(W);
  router_mfma_kernel<<<T_DIM / ROWS, 256, 0, stream>>>(h, bias, out, flags);
  router_fixup_kernel<<<T_DIM, 512, 0, stream>>>(h, W, bias, flags, out);
}

// Round 9
// 271.751 us; speedup vs baseline: 1.1687x; 1.1687x over previous
//
#include <hip/hip_runtime.h>
#include <stdint.h>
#include <math.h>

#define T_DIM 8192
#define D_DIM 4096
#define E_DIM 64
#define TE (T_DIM * E_DIM)  // 524288
#define GAP_MARGIN 2e-3     // >= 2x provable worst-case bf16-split logit error (9.4e-4)
#define ROWS 32             // rows per block (mfma kernel)
#define BK 128              // k per chunk
#define NCHUNK (D_DIM / BK) // 32

typedef __attribute__((ext_vector_type(8))) short short8_t;  // 8 bf16 (4 VGPRs)
typedef __attribute__((ext_vector_type(4))) float f32x4;

// Raw barrier: LDS-drain only. Does NOT drain vmcnt -> A-prefetch regs and
// B global_load_lds DMAs stay in flight across chunk barriers.
#define BAR() do {                                            \
    asm volatile("s_waitcnt lgkmcnt(0)" ::: "memory");        \
    __builtin_amdgcn_s_barrier();                             \
    asm volatile("" ::: "memory");                            \
  } while (0)

// global -> LDS direct DMA, 16B per lane. dest base must be wave-uniform;
// HW writes lane i at lds_base + i*16. Zero VGPR cost, tracked by vmcnt.
__device__ __forceinline__ void gload16(const void* g, void* l) {
  __builtin_amdgcn_global_load_lds(
      (const __attribute__((address_space(1))) uint32_t*)g,
      (__attribute__((address_space(3))) uint32_t*)l, 16, 0, 0);
}

// ============================================================================
// W bf16 hi/lo planes, CHUNK-CONTIGUOUS fragment order (new in round 9):
// idx(e,k) = (k>>3)*512 + (e>>4)*128 + (e&15)*8 + (k&7).
// Chunk c (128 k) occupies shorts [c*8192, c*8192+8192) = 16 KB contiguous ->
// loaded by 16 global_load_lds (2 per wave per plane) straight into LDS with
// fragment addressing preserved: frag offset = koct*512 + n*128 + ee*8.
// ============================================================================
__device__ __align__(16) short Whi_g[E_DIM * D_DIM];  // 512 KB
__device__ __align__(16) short Wlo_g[E_DIM * D_DIM];  // 512 KB

// ============================================================================
// Threefry-2x32, key = (0, 42), 20 rounds — VALIDATED (prior session)
// ============================================================================
__device__ __forceinline__ void threefry2x32_k42(uint32_t x0, uint32_t x1,
                                                 uint32_t& o0, uint32_t& o1) {
  const uint32_t ks0 = 0u, ks1 = 42u;
  const uint32_t ks2 = 0x1BD11BDAu ^ ks0 ^ ks1;
  x0 += ks0; x1 += ks1;
#define TF_RND(r) { x0 += x1; x1 = (x1 << (r)) | (x1 >> (32 - (r))); x1 ^= x0; }
  TF_RND(13) TF_RND(15) TF_RND(26) TF_RND(6)   x0 += ks1; x1 += ks2 + 1u;
  TF_RND(17) TF_RND(29) TF_RND(16) TF_RND(24)  x0 += ks2; x1 += ks0 + 2u;
  TF_RND(13) TF_RND(15) TF_RND(26) TF_RND(6)   x0 += ks0; x1 += ks1 + 3u;
  TF_RND(17) TF_RND(29) TF_RND(16) TF_RND(24)  x0 += ks1; x1 += ks2 + 4u;
  TF_RND(13) TF_RND(15) TF_RND(26) TF_RND(6)   x0 += ks2; x1 += ks0 + 5u;
#undef TF_RND
  o0 = x0; o1 = x1;
}

__device__ __forceinline__ uint32_t jax_random_bits32(uint32_t j) {
  uint32_t o0, o1;
  threefry2x32_k42(0u, j, o0, o1);
  return o0 ^ o1;
}

// Gumbel noise g for flat index idx — EXACT transcription of the validated
// finalize path (used by both mfma finalize and fixup).
__device__ __forceinline__ double gumbel_f64(int idx) {
  const uint32_t bits = jax_random_bits32((uint32_t)idx);
  const float f01 = __uint_as_float((bits >> 9) | 0x3f800000u) - 1.0f;
  const float minv = 1e-6f;
  const float maxv = 0.999999f;
  float u = __fadd_rn(__fmul_rn(f01, maxv - minv), minv);
  u = fmaxf(minv, u);
  return -log(-log((double)u));
}

// f64 finalize per row (lane = expert) — VALIDATED, unchanged
__device__ __forceinline__ void finalize_row_f64(double logit, int e, int t,
                                                 float& mask_out, float& weight_out,
                                                 double& gap_out) {
  double m = logit;
#pragma unroll
  for (int off = 1; off < 64; off <<= 1) {
    const double om = __shfl_xor(m, off, 64);
    m = (om > m) ? om : m;
  }
  const double pe = exp(logit - m);
  double s = pe;
#pragma unroll
  for (int off = 1; off < 64; off <<= 1) s += __shfl_xor(s, off, 64);
  weight_out = (float)(pe / s);

  const double g = gumbel_f64(t * 64 + e);
  const double sel = logit + g;

  float mask = 0.0f;
  double cur = sel;
  double v8 = 0.0, v9 = 0.0;
  for (int it = 0; it < 9; ++it) {
    double v = cur;
    int vi = e;
#pragma unroll
    for (int off = 1; off < 64; off <<= 1) {
      const double ov = __shfl_xor(v, off, 64);
      const int    oi = __shfl_xor(vi, off, 64);
      if (ov > v || (ov == v && oi < vi)) { v = ov; vi = oi; }
    }
    if (it < 8) {
      if (vi == e) { mask = 1.0f; cur = -__builtin_inf(); }
      if (it == 7) v8 = v;
    } else {
      v9 = v;
    }
  }
  mask_out = mask;
  gap_out = v8 - v9;
}

// fp32 -> bf16 (RNE, finite inputs only)
__device__ __forceinline__ uint16_t f2bf(float f) {
  const uint32_t x = __float_as_uint(f);
  return (uint16_t)((x + 0x7FFFu + ((x >> 16) & 1u)) >> 16);
}

// split 8 consecutive floats into bf16 hi/lo short8 fragments
__device__ __forceinline__ void split8(const float4 a, const float4 b,
                                       short8_t& hi, short8_t& lo) {
  const float f[8] = {a.x, a.y, a.z, a.w, b.x, b.y, b.z, b.w};
#pragma unroll
  for (int j = 0; j < 8; ++j) {
    const uint16_t hb = f2bf(f[j]);
    const float fh = __uint_as_float((uint32_t)hb << 16);
    const uint16_t lb = f2bf(f[j] - fh);
    hi[j] = (short)hb;
    lo[j] = (short)lb;
  }
}

// ============================================================================
// Pre-kernel: split W into bf16 hi/lo planes, chunk-contiguous order.
// ============================================================================
__global__ __launch_bounds__(256)
void w_split_kernel(const float* __restrict__ W) {
  const int g = blockIdx.x * 256 + threadIdx.x;  // 0..16383
#pragma unroll
  for (int r = 0; r < 2; ++r) {
    const int u = g * 2 + r;        // unit id 0..32767 (one unit = 8 k of one e)
    const int e = u >> 9;
    const int k0 = (u & 511) * 8;
    const float* wp = W + (size_t)e * D_DIM + k0;
    const float4 a = *reinterpret_cast<const float4*>(wp);
    const float4 b = *reinterpret_cast<const float4*>(wp + 4);
    short8_t hi, lo;
    split8(a, b, hi, lo);
    const int idx = (k0 >> 3) * 512 + (e >> 4) * 128 + (e & 15) * 8;
    *reinterpret_cast<short8_t*>(Whi_g + idx) = hi;
    *reinterpret_cast<short8_t*>(Wlo_g + idx) = lo;
  }
}

// ============================================================================
// MFMA router kernel. 256 blocks x 512 threads (8 waves = 2m x 4n). Block:
// 32 rows x 64 e; wave (m=wv>>2, n=wv&3) owns one 16x16 tile. Validated
// 3-product split, identical accumulation order -> bitwise-identical logits.
//
// B: global_load_lds DMA into TRI-buffered LDS (96 KB), issued 2 chunks
//    ahead. No VGPRs, no allocator games (the round-5/7/8 failure mode).
//    Drain logic is FREE: split(c) auto-waits A-regs(c), which were issued
//    immediately AFTER B-DMA(c) -> FIFO vmcnt drains B-DMA(c) too. B-DMA(c+1)
//    (issued after A-regs(c)) stays in flight. Zero manual vmcnt.
// A: r7-proven path, BK=128: thread owns (row=tid>>4, koct=tid&15); reads
//    coalesced 32B, splits once per element, ds_write_b128 x2 at XOR-swizzled
//    unit u^=( u>>5)&7 (write: 8 bank-groups x2 = b128 minimum; read same).
//    Depth-2 register prefetch survives BAR (no vmcnt drain).
// One BAR per chunk. Race audit: A dbuf write@c vs reads@c-2 separated by
// BAR@c-1 (lgkm drained); B tri-buf DMA(c+2) issued after BAR@c, readers of
// that buffer were @c-1 and completed before BAR@c. LDS 136.3 KB -> 1 blk/CU.
// ============================================================================
__global__ __launch_bounds__(512)
void router_mfma_kernel(const float* __restrict__ h,
                        const float* __restrict__ bias,
                        float* __restrict__ out,
                        unsigned char* __restrict__ flags) {
  __shared__ __align__(16) short Ahi[2][ROWS * BK];   // 2 x 8 KB
  __shared__ __align__(16) short Alo[2][ROWS * BK];   // 2 x 8 KB
  __shared__ __align__(16) short Bhi[3][E_DIM * BK];  // 3 x 16 KB
  __shared__ __align__(16) short Blo[3][E_DIM * BK];  // 3 x 16 KB
  __shared__ float logits_lds[ROWS * 65];             // 8.3 KB

  const int tid  = threadIdx.x;
  const int wv   = tid >> 6;
  const int lane = tid & 63;
  const int m    = wv >> 2;    // 0..1
  const int n    = wv & 3;     // 0..3
  const int row0 = blockIdx.x * ROWS;

  // A staging: thread -> (row r, k-octet koct_w) of each chunk
  const int r      = tid >> 4;          // 0..31
  const int koct_w = tid & 15;          // 0..15
  const int u0w    = koct_w * 32 + r;
  const int uW     = u0w ^ ((u0w >> 5) & 7);   // bank swizzle (both sides)
  const float* hst = h + (size_t)(row0 + r) * D_DIM + koct_w * 8;

  // fragment read bases
  const int mrow  = m * 16 + (lane & 15);      // A row within block
  const int nb128 = n * 128 + (lane & 15) * 8; // B inner offset

  f32x4 acc = {0.0f, 0.0f, 0.0f, 0.0f};

  // B DMA for chunk cc into buffer bb: 2 planes x 2 instr per wave
  auto bdma = [&](int cc, int bb) {
    const size_t cb = (size_t)cc * 8192;
#pragma unroll
    for (int i = 0; i < 2; ++i) {
      const int so = wv * 1024 + i * 512;      // shorts; wave-uniform
      gload16(Whi_g + cb + so + lane * 8, &Bhi[bb][so]);
      gload16(Wlo_g + cb + so + lane * 8, &Blo[bb][so]);
    }
  };

  // prologue: B-DMA(c) BEFORE A-load(c) so split(c)'s auto-wait drains it
  bdma(0, 0);
  float4 Ra0 = *reinterpret_cast<const float4*>(hst);
  float4 Ra1 = *reinterpret_cast<const float4*>(hst + 4);
  bdma(1, 1);
  float4 Rb0 = *reinterpret_cast<const float4*>(hst + BK);
  float4 Rb1 = *reinterpret_cast<const float4*>(hst + BK + 4);

#define CHUNK_BODY(R0, R1, CC)                                                 \
  {                                                                            \
    const int buf_  = (CC) & 1;                                                \
    const int bbuf_ = (CC) % 3;                                                \
    short8_t hi_, lo_;                                                         \
    split8(R0, R1, hi_, lo_);   /* auto vmcnt wait drains B-DMA(CC) too */     \
    *reinterpret_cast<short8_t*>(&Ahi[buf_][uW * 8]) = hi_;                    \
    *reinterpret_cast<short8_t*>(&Alo[buf_][uW * 8]) = lo_;                    \
    BAR();                                                                     \
    if ((CC) + 2 < NCHUNK) {                                                   \
      const int cn_ = (CC) + 2;                                                \
      bdma(cn_, cn_ % 3);            /* B first...        */                   \
      const float* p_ = hst + cn_ * BK;                                        \
      R0 = *reinterpret_cast<const float4*>(p_);      /* ...then A regs */     \
      R1 = *reinterpret_cast<const float4*>(p_ + 4);                           \
    }                                                                          \
    _Pragma("unroll")                                                          \
    for (int s_ = 0; s_ < BK / 32; ++s_) {                                     \
      const int koct_ = s_ * 4 + (lane >> 4);                                  \
      const int u0_   = koct_ * 32 + mrow;                                     \
      const int ua_   = u0_ ^ ((u0_ >> 5) & 7);                                \
      const short8_t ah_ = *reinterpret_cast<const short8_t*>(&Ahi[buf_][ua_ * 8]); \
      const short8_t al_ = *reinterpret_cast<const short8_t*>(&Alo[buf_][ua_ * 8]); \
      const int bo_ = koct_ * 512 + nb128;                                     \
      const short8_t bh_ = *reinterpret_cast<const short8_t*>(&Bhi[bbuf_][bo_]); \
      const short8_t bl_ = *reinterpret_cast<const short8_t*>(&Blo[bbuf_][bo_]); \
      acc = __builtin_amdgcn_mfma_f32_16x16x32_bf16(al_, bh_, acc, 0, 0, 0);   \
      acc = __builtin_amdgcn_mfma_f32_16x16x32_bf16(ah_, bl_, acc, 0, 0, 0);   \
      acc = __builtin_amdgcn_mfma_f32_16x16x32_bf16(ah_, bh_, acc, 0, 0, 0);   \
    }                                                                          \
  }

  for (int c = 0; c < NCHUNK; c += 2) {
    CHUNK_BODY(Ra0, Ra1, c)
    CHUNK_BODY(Rb0, Rb1, c + 1)
  }
#undef CHUNK_BODY

  // epilogue: C/D layout col=lane&15, row=(lane>>4)*4+reg -> logits LDS
  {
    const int q   = lane >> 4;
    const int col = n * 16 + (lane & 15);
#pragma unroll
    for (int reg = 0; reg < 4; ++reg) {
      logits_lds[(m * 16 + q * 4 + reg) * 65 + col] = acc[reg];
    }
  }
  __syncthreads();

  // finalize: wave handles rows 4*wv..+3, lane = expert — VALIDATED path
  const int e = lane;
  const double be = (double)bias[e];
  for (int rr = 0; rr < 4; ++rr) {
    const int rloc = wv * 4 + rr;
    const int t = row0 + rloc;
    const double logit = (double)logits_lds[rloc * 65 + e] + be;

    float mask, weight;
    double gap;
    finalize_row_f64(logit, e, t, mask, weight, gap);

    const int idx = t * 64 + e;
    out[idx]          = mask;
    out[TE + idx]     = weight;
    out[2 * TE + idx] = (float)logit;
    if (e == 0) flags[t] = (gap < GAP_MARGIN) ? 1 : 0;
  }
}

// ============================================================================
// Fixup kernel — CANDIDATE-WINDOW redesign. Provable: an expert with approx
// sel < v9a - 2e-3 cannot be in the true top-8 (per-expert |sel error| <=
// 9.4e-4, so 2*delta = 1.88e-3 <= 2e-3 window; the >=9 experts at/above v9a
// all beat it). So: recompute EXACT f64 logits only for the ~9-12 candidates
// (~170 KB instead of 1 MB+scatter per row), re-rank exactly, rewrite the
// MASK row only. Weight/logit outputs keep the mfma kernel's values — same
// approximation class as every unflagged row (within tolerance by the same
// argument). Tie-break: smaller index, identical to the validated finalize.
// ============================================================================
__global__ __launch_bounds__(256)
void router_fixup_kernel(const float* __restrict__ h,
                         const float* __restrict__ W,
                         const float* __restrict__ bias,
                         const unsigned char* __restrict__ flags,
                         float* __restrict__ out) {
  const int t = blockIdx.x;
  if (flags[t] == 0) return;

  __shared__ float  h_lds[D_DIM];   // 16 KB
  __shared__ double red4[4];
  __shared__ double sel_ex[64];
  __shared__ unsigned long long cmask_lds;

  const int tid  = threadIdx.x;
  const int wv   = tid >> 6;
  const int lane = tid & 63;

  // stage h row (256 thr x 4 float4, coalesced)
  const float4* hr4 = reinterpret_cast<const float4*>(h + (size_t)t * D_DIM);
  float4* hl4 = reinterpret_cast<float4*>(h_lds);
#pragma unroll
  for (int i = 0; i < 4; ++i) hl4[tid + 256 * i] = hr4[tid + 256 * i];

  // wave 0: approx sel from stored logits, find v9a, build candidate mask
  if (wv == 0) {
    const int e = lane;
    const double sela = (double)out[2 * TE + t * 64 + e] + gumbel_f64(t * 64 + e);
    double cur = sela;
    double v9 = 0.0;
    for (int it = 0; it < 9; ++it) {
      double v = cur;
      int vi = e;
#pragma unroll
      for (int off = 1; off < 64; off <<= 1) {
        const double ov = __shfl_xor(v, off, 64);
        const int    oi = __shfl_xor(vi, off, 64);
        if (ov > v || (ov == v && oi < vi)) { v = ov; vi = oi; }
      }
      if (it < 8) { if (vi == e) cur = -__builtin_inf(); }
      else v9 = v;
    }
    const bool cand = (sela >= v9 - GAP_MARGIN);
    const unsigned long long cm = __ballot(cand);
    sel_ex[e] = sela;                 // candidates overwritten with exact below
    if (lane == 0) cmask_lds = cm;
  }
  __syncthreads();
  const unsigned long long cmask = cmask_lds;

  // exact f64 dot for each candidate (block-cooperative, coalesced W reads)
  for (unsigned long long mm = cmask; mm; mm &= mm - 1) {
    const int e = (int)(__ffsll((long long)mm) - 1);
    const float4* wr4 = reinterpret_cast<const float4*>(W + (size_t)e * D_DIM);
    double a0 = 0.0, a1 = 0.0, a2 = 0.0, a3 = 0.0;
#pragma unroll
    for (int i = 0; i < 4; ++i) {
      const float4 w  = wr4[tid + 256 * i];
      const float4 hh = hl4[tid + 256 * i];
      a0 = fma((double)w.x, (double)hh.x, a0);
      a1 = fma((double)w.y, (double)hh.y, a1);
      a2 = fma((double)w.z, (double)hh.z, a2);
      a3 = fma((double)w.w, (double)hh.w, a3);
    }
    double s = (a0 + a1) + (a2 + a3);
#pragma unroll
    for (int off = 1; off < 64; off <<= 1) s += __shfl_xor(s, off, 64);
    if (lane == 0) red4[wv] = s;
    __syncthreads();
    if (tid == 0) {
      const double dot = (red4[0] + red4[1]) + (red4[2] + red4[3]);
      sel_ex[e] = (dot + (double)bias[e]) + gumbel_f64(t * 64 + e);
    }
    __syncthreads();
  }

  // wave 0: exact top-8 among candidates -> rewrite mask row
  if (wv == 0) {
    const int e = lane;
    const bool cand = (cmask >> e) & 1ULL;
    double cur = cand ? sel_ex[e] : -__builtin_inf();
    float mask = 0.0f;
    for (int it = 0; it < 8; ++it) {
      double v = cur;
      int vi = e;
#pragma unroll
      for (int off = 1; off < 64; off <<= 1) {
        const double ov = __shfl_xor(v, off, 64);
        const int    oi = __shfl_xor(vi, off, 64);
        if (ov > v || (ov == v && oi < vi)) { v = ov; vi = oi; }
      }
      if (vi == e) { mask = 1.0f; cur = -__builtin_inf(); }
    }
    out[t * 64 + e] = mask;
  }
}

extern "C" void kernel_launch(void* const* d_in, const int* in_sizes, int n_in,
                              void* d_out, int out_size, void* d_ws, size_t ws_size,
                              hipStream_t stream) {
  const float* h    = (const float*)d_in[0];
  const float* W    = (const float*)d_in[1];
  const float* bias = (const float*)d_in[2];
  // d_in[3] = k (always 8) — hard-coded top-8
  float* out = (float*)d_out;
  unsigned char* flags = (unsigned char*)d_ws;  // 8192 B, fully rewritten per call

  w_split_kernel<<<64, 256, 0, stream>>>(W);
  router_mfma_kernel<<<T_DIM / ROWS, 512, 0, stream>>>(h, bias, out, flags);
  router_fixup_kernel<<<T_DIM, 256, 0, stream>>>(h, W, bias, flags, out);
}